// Round 5
// baseline (197.366 us; speedup 1.0000x reference)
//
#include <hip/hip_runtime.h>

typedef unsigned char u8;
typedef float fp32x4 __attribute__((ext_vector_type(4)));

#define BS 4096
#define NROW 8192
#define D 512
#define TILE 128
#define BK 64                     // k-bytes staged per iter (fp8)
#define NB (NROW / TILE)          // 64 block-rows/cols
#define NBLK (NB * (NB + 1) / 2)  // 2080 upper-triangle blocks
#define INV_T 10.0f

__device__ __forceinline__ void g2l16(const void* g, void* l) {
  __builtin_amdgcn_global_load_lds(
      (const __attribute__((address_space(1))) unsigned int*)g,
      (__attribute__((address_space(3))) unsigned int*)l, 16, 0, 0);
}

// Wave-per-row normalize -> fp8 e4m3 (An is 4 MB: XCD-L2 resident).
// Also zeroes den/posAcc/counter (ws is re-poisoned before every launch).
__global__ __launch_bounds__(256) void normalize_k(
    const float* __restrict__ zi, const float* __restrict__ zj,
    u8* __restrict__ An, float* __restrict__ den, float* __restrict__ posAcc,
    unsigned int* __restrict__ counter) {
  const int lane = threadIdx.x & 63;
  const int wave = threadIdx.x >> 6;
  const int r = blockIdx.x * 4 + wave;
  const float* src = (r < BS) ? (zi + (size_t)r * D) : (zj + (size_t)(r - BS) * D);
  const float4 v0 = ((const float4*)src)[lane * 2];
  const float4 v1 = ((const float4*)src)[lane * 2 + 1];
  float ss = v0.x * v0.x + v0.y * v0.y + v0.z * v0.z + v0.w * v0.w +
             v1.x * v1.x + v1.y * v1.y + v1.z * v1.z + v1.w * v1.w;
#pragma unroll
  for (int off = 1; off < 64; off <<= 1) ss += __shfl_xor(ss, off);
  const float inv = 1.0f / fmaxf(sqrtf(ss), 1e-8f);
  int lo = __builtin_amdgcn_cvt_pk_fp8_f32(v0.x * inv, v0.y * inv, 0, false);
  lo = __builtin_amdgcn_cvt_pk_fp8_f32(v0.z * inv, v0.w * inv, lo, true);
  int hi = __builtin_amdgcn_cvt_pk_fp8_f32(v1.x * inv, v1.y * inv, 0, false);
  hi = __builtin_amdgcn_cvt_pk_fp8_f32(v1.z * inv, v1.w * inv, hi, true);
  ((int2*)(An + (size_t)r * D))[lane] = make_int2(lo, hi);
  if (lane == 0) den[r] = 0.0f;
  if (r == 0 && lane == 0) {
    posAcc[0] = 0.0f;
    counter[0] = 0u;
  }
}

// Upper-triangle (bi<=bj) 128x128 tiles of sim = An*An^T, fp8 MFMA,
// double-buffered LDS (2 x 16 KB): g2l for tile k+1 issued right after the
// barrier, overlapping L2 latency with ds_read + 32 MFMA.
// Off-diagonal tiles: den[row] += rowsum(exp), den[col] += colsum(exp).
// Diagonal tiles: den[row] += rowsum(exp), row==col masked.
// posAcc += sim/T over entries col == row+BS (upper copy; doubled at the end).
// Last block to finish (device-scope counter) computes the final loss.
__global__ __launch_bounds__(256) void gemm_expsum(
    const u8* __restrict__ An, float* __restrict__ den,
    float* __restrict__ posAcc, unsigned int* __restrict__ counter,
    float* __restrict__ out) {
  __shared__ __align__(16) u8 sA[2][TILE * BK];  // 2 x 8 KB
  __shared__ __align__(16) u8 sB[2][TILE * BK];  // 2 x 8 KB

  // linear triangle order: consecutive blocks share the A-strip (L2 reuse)
  int rem = blockIdx.x;
  int bi = 0;
  while (rem >= NB - bi) { rem -= NB - bi; ++bi; }
  const int bj = bi + rem;
  const bool diag = (bi == bj);
  const int rowBase = bi * TILE;
  const int colBase = bj * TILE;

  const int tid = threadIdx.x;
  const int lane = tid & 63;
  const int wave = tid >> 6;
  const int wr = wave >> 1;
  const int wc = wave & 1;

  fp32x4 acc[4][4] = {};

  // staging: 512 16B chunks per tile (4 chunks per 64B row-slab); LDS slot
  // (row, s) holds global chunk s ^ (row&3). The byte-granular XOR (vs
  // (row>>1)&3 in R4) puts the b64 fragment reads at the 4-cycle floor:
  // 16 buckets x 4 lanes, zero conflict cycles.
  const int c0 = tid;
  const int c1 = tid + 256;
  const int r0 = c0 >> 2, g0 = (c0 & 3) ^ (r0 & 3);
  const int r1 = c1 >> 2, g1 = (c1 & 3) ^ (r1 & 3);
  const u8* gA0 = An + (size_t)(rowBase + r0) * D + g0 * 16;
  const u8* gA1 = An + (size_t)(rowBase + r1) * D + g1 * 16;
  const u8* gB0 = An + (size_t)(colBase + r0) * D + g0 * 16;
  const u8* gB1 = An + (size_t)(colBase + r1) * D + g1 * 16;

  const int fr = lane & 15;  // A row / B col within 16-tile
  const int h = lane >> 4;   // k-group 0..3 (8 fp8 each per K=32 sub)
  const int w8 = (h & 1) * 8;
  const int hc = h >> 1;     // chunk half-index within a sub

  // Prologue: stage tile k=0 into buffer 0.
  g2l16(gA0, sA[0] + c0 * 16);
  g2l16(gA1, sA[0] + c1 * 16);
  g2l16(gB0, sB[0] + c0 * 16);
  g2l16(gB1, sB[0] + c1 * 16);

  int cur = 0;
  for (int k0 = 0; k0 < D; k0 += BK, cur ^= 1) {
    __syncthreads();  // drains vmcnt: buf[cur] ready; buf[cur^1] free
    const int nk = k0 + BK;
    if (nk < D) {
      g2l16(gA0 + nk, sA[cur ^ 1] + c0 * 16);
      g2l16(gA1 + nk, sA[cur ^ 1] + c1 * 16);
      g2l16(gB0 + nk, sB[cur ^ 1] + c0 * 16);
      g2l16(gB1 + nk, sB[cur ^ 1] + c1 * 16);
    }
#pragma unroll
    for (int sub = 0; sub < 2; ++sub) {
      const int cb = sub * 2 + hc;  // chunk holding this lane's 8 k-bytes
      long a[4], b[4];
#pragma unroll
      for (int i = 0; i < 4; ++i) {
        const int ra = wr * 64 + i * 16 + fr;
        const int rb = wc * 64 + i * 16 + fr;
        a[i] = *(const long*)(sA[cur] + ra * BK + (cb ^ (ra & 3)) * 16 + w8);
        b[i] = *(const long*)(sB[cur] + rb * BK + (cb ^ (rb & 3)) * 16 + w8);
      }
#pragma unroll
      for (int i = 0; i < 4; ++i)
#pragma unroll
        for (int j = 0; j < 4; ++j)
          acc[i][j] = __builtin_amdgcn_mfma_f32_16x16x32_fp8_fp8(
              a[i], b[j], acc[i][j], 0, 0, 0);
    }
  }

  // Epilogue. C/D layout (16x16 shapes, dtype-independent):
  // col = lane&15, row = (lane>>4)*4 + reg.
  const int rq = h * 4;
  float posPart = 0.0f;
  float colAcc[4] = {0.0f, 0.0f, 0.0f, 0.0f};
#pragma unroll
  for (int i = 0; i < 4; ++i) {
    const int rbase = rowBase + wr * 64 + i * 16 + rq;
    float rs[4] = {0.0f, 0.0f, 0.0f, 0.0f};
#pragma unroll
    for (int j = 0; j < 4; ++j) {
      const int colg = colBase + wc * 64 + j * 16 + fr;
      fp32x4 v = acc[i][j];
#pragma unroll
      for (int rg = 0; rg < 4; ++rg) {
        const int rowg = rbase + rg;
        const float sv = v[rg] * INV_T;
        float e = __expf(sv);
        if (diag && rowg == colg) e = 0.0f;  // exclude matrix diagonal exactly
        rs[rg] += e;
        colAcc[j] += e;
        if (colg == rowg + BS) posPart += sv;  // upper copy only; doubled later
      }
    }
#pragma unroll
    for (int rg = 0; rg < 4; ++rg) {
      float s = rs[rg];
      s += __shfl_xor(s, 1);
      s += __shfl_xor(s, 2);
      s += __shfl_xor(s, 4);
      s += __shfl_xor(s, 8);
      if (fr == 0) atomicAdd(&den[rbase + rg], s);
    }
  }
  if (!diag) {
#pragma unroll
    for (int j = 0; j < 4; ++j) {
      float c = colAcc[j];
      c += __shfl_xor(c, 16);
      c += __shfl_xor(c, 32);
      if (h == 0) atomicAdd(&den[colBase + wc * 64 + j * 16 + fr], c);
    }
  }
  posPart += __shfl_xor(posPart, 1);
  posPart += __shfl_xor(posPart, 2);
  posPart += __shfl_xor(posPart, 4);
  posPart += __shfl_xor(posPart, 8);
  posPart += __shfl_xor(posPart, 16);
  posPart += __shfl_xor(posPart, 32);
  if (lane == 0 && posPart != 0.0f) atomicAdd(posAcc, posPart);

  // ---- last-block finalize (replaces the finalize_k dispatch) ----
  __shared__ bool lastFlag;
  __syncthreads();  // all this block's den/posAcc atomics drained (vmcnt)
  if (tid == 0) {
    __threadfence();
    unsigned int old = __hip_atomic_fetch_add(counter, 1u, __ATOMIC_ACQ_REL,
                                              __HIP_MEMORY_SCOPE_AGENT);
    lastFlag = (old == NBLK - 1);
  }
  __syncthreads();
  if (lastFlag) {
    // every other block has completed its den atomics; read at agent scope
    float s = 0.0f;
    for (int i = tid; i < NROW; i += 256)
      s += logf(__hip_atomic_load(&den[i], __ATOMIC_RELAXED,
                                  __HIP_MEMORY_SCOPE_AGENT));
#pragma unroll
    for (int off = 1; off < 64; off <<= 1) s += __shfl_xor(s, off);
    __shared__ float wsum[4];
    if ((tid & 63) == 0) wsum[tid >> 6] = s;
    __syncthreads();
    if (tid == 0) {
      const float tot = wsum[0] + wsum[1] + wsum[2] + wsum[3];
      const float pos = __hip_atomic_load(posAcc, __ATOMIC_RELAXED,
                                          __HIP_MEMORY_SCOPE_AGENT);
      out[0] = (tot - 2.0f * pos) * (1.0f / (float)NROW);
    }
  }
}

extern "C" void kernel_launch(void* const* d_in, const int* in_sizes, int n_in,
                              void* d_out, int out_size, void* d_ws, size_t ws_size,
                              hipStream_t stream) {
  const float* zi = (const float*)d_in[0];
  const float* zj = (const float*)d_in[1];
  float* out = (float*)d_out;

  u8* An = (u8*)d_ws;                                     // 4 MB fp8 normalized reps
  float* den = (float*)((char*)d_ws + (size_t)NROW * D);  // 8192 fp32
  float* posAcc = den + NROW;                             // 1 fp32
  unsigned int* counter = (unsigned int*)(posAcc + 1);    // 1 u32

  normalize_k<<<NROW / 4, 256, 0, stream>>>(zi, zj, An, den, posAcc, counter);
  gemm_expsum<<<NBLK, 256, 0, stream>>>(An, den, posAcc, counter, out);
}

// Round 6
// 193.905 us; speedup vs baseline: 1.0178x; 1.0178x over previous
//
#include <hip/hip_runtime.h>

typedef unsigned char u8;
typedef float fp32x4 __attribute__((ext_vector_type(4)));
typedef int i32x4 __attribute__((ext_vector_type(4)));
typedef int i32x8 __attribute__((ext_vector_type(8)));

#define BS 4096
#define NROW 8192
#define D 512
#define TILE 128
#define BK 128                    // k-bytes staged per iter (fp8)
#define NB (NROW / TILE)          // 64 block-rows/cols
#define NBLK (NB * (NB + 1) / 2)  // 2080 upper-triangle blocks
#define INV_T 10.0f
#define SCALE1 0x7f7f7f7f         // E8M0 127 = 2^0 in every byte

__device__ __forceinline__ void g2l16(const void* g, void* l) {
  __builtin_amdgcn_global_load_lds(
      (const __attribute__((address_space(1))) unsigned int*)g,
      (__attribute__((address_space(3))) unsigned int*)l, 16, 0, 0);
}

// Wave-per-row normalize -> fp8 e4m3 (An is 4 MB: XCD-L2 resident).
// Also zeroes den/posAcc/counter (ws is re-poisoned before every launch).
__global__ __launch_bounds__(256) void normalize_k(
    const float* __restrict__ zi, const float* __restrict__ zj,
    u8* __restrict__ An, float* __restrict__ den, float* __restrict__ posAcc,
    unsigned int* __restrict__ counter) {
  const int lane = threadIdx.x & 63;
  const int wave = threadIdx.x >> 6;
  const int r = blockIdx.x * 4 + wave;
  const float* src = (r < BS) ? (zi + (size_t)r * D) : (zj + (size_t)(r - BS) * D);
  const float4 v0 = ((const float4*)src)[lane * 2];
  const float4 v1 = ((const float4*)src)[lane * 2 + 1];
  float ss = v0.x * v0.x + v0.y * v0.y + v0.z * v0.z + v0.w * v0.w +
             v1.x * v1.x + v1.y * v1.y + v1.z * v1.z + v1.w * v1.w;
#pragma unroll
  for (int off = 1; off < 64; off <<= 1) ss += __shfl_xor(ss, off);
  const float inv = 1.0f / fmaxf(sqrtf(ss), 1e-8f);
  int lo = __builtin_amdgcn_cvt_pk_fp8_f32(v0.x * inv, v0.y * inv, 0, false);
  lo = __builtin_amdgcn_cvt_pk_fp8_f32(v0.z * inv, v0.w * inv, lo, true);
  int hi = __builtin_amdgcn_cvt_pk_fp8_f32(v1.x * inv, v1.y * inv, 0, false);
  hi = __builtin_amdgcn_cvt_pk_fp8_f32(v1.z * inv, v1.w * inv, hi, true);
  ((int2*)(An + (size_t)r * D))[lane] = make_int2(lo, hi);
  if (lane == 0) den[r] = 0.0f;
  if (r == 0 && lane == 0) {
    posAcc[0] = 0.0f;
    counter[0] = 0u;
  }
}

// Upper-triangle (bi<=bj) 128x128 tiles of sim = An*An^T using MX-scaled fp8
// MFMA (K=128, scales pinned to 1.0). Single-buffered LDS, 2-barrier K-loop
// (empirically best: dbuf regressed in R3 and R5 — TLP does latency hiding).
// Off-diagonal tiles: den[row] += rowsum(exp), den[col] += colsum(exp).
// Diagonal tiles: den[row] += rowsum(exp), row==col masked.
// posAcc += sim/T over entries col == row+BS (upper copy; doubled at the end).
// Last block to finish (agent-scope counter) computes the final loss.
__global__ __launch_bounds__(256) void gemm_expsum(
    const u8* __restrict__ An, float* __restrict__ den,
    float* __restrict__ posAcc, unsigned int* __restrict__ counter,
    float* __restrict__ out) {
  __shared__ __align__(16) u8 sA[TILE * BK];  // 16 KB
  __shared__ __align__(16) u8 sB[TILE * BK];  // 16 KB

  // linear triangle order: consecutive blocks share the A-strip (L2 reuse)
  int rem = blockIdx.x;
  int bi = 0;
  while (rem >= NB - bi) { rem -= NB - bi; ++bi; }
  const int bj = bi + rem;
  const bool diag = (bi == bj);
  const int rowBase = bi * TILE;
  const int colBase = bj * TILE;

  const int tid = threadIdx.x;
  const int lane = tid & 63;
  const int wave = tid >> 6;
  const int wr = wave >> 1;
  const int wc = wave & 1;

  fp32x4 acc[4][4] = {};

  // Staging: tile = 128 rows x 8 chunks of 16B. LDS slot s holds global chunk
  // (row = s>>3, col = (s&7) ^ (row&7)). The 3-bit xor + 128B row stride
  // (== 0 mod 32 banks) makes every fragment b128 phase hit each bank exactly
  // twice — the measured-conflict-free R2 pattern.
  const u8* gA[4];
  const u8* gB[4];
  u8* lA[4];
  u8* lB[4];
#pragma unroll
  for (int j = 0; j < 4; ++j) {
    const int s = tid + 256 * j;
    const int rs = s >> 3;
    const int cs = (s & 7) ^ (rs & 7);
    gA[j] = An + (size_t)(rowBase + rs) * D + cs * 16;
    gB[j] = An + (size_t)(colBase + rs) * D + cs * 16;
    lA[j] = sA + s * 16;
    lB[j] = sB + s * 16;
  }

  const int fr = lane & 15;  // A row / B col within 16-tile
  const int h = lane >> 4;   // k-block 0..3 (32 fp8 bytes each)
  const int hb = 2 * h;      // first of the lane's two 16B chunk-columns

  for (int k0 = 0; k0 < D; k0 += BK) {
#pragma unroll
    for (int j = 0; j < 4; ++j) {
      g2l16(gA[j] + k0, lA[j]);
      g2l16(gB[j] + k0, lB[j]);
    }
    __syncthreads();  // drains vmcnt -> LDS tiles complete

    i32x8 a[4];
#pragma unroll
    for (int i = 0; i < 4; ++i) {
      const int rA = wr * 64 + i * 16 + fr;
      const int cl = hb ^ (rA & 7);
      const i32x4 lo = *(const i32x4*)(sA + (rA * 8 + cl) * 16);
      const i32x4 hi = *(const i32x4*)(sA + (rA * 8 + (cl ^ 1)) * 16);
      a[i][0] = lo[0]; a[i][1] = lo[1]; a[i][2] = lo[2]; a[i][3] = lo[3];
      a[i][4] = hi[0]; a[i][5] = hi[1]; a[i][6] = hi[2]; a[i][7] = hi[3];
    }
#pragma unroll
    for (int j = 0; j < 4; ++j) {
      const int rB = wc * 64 + j * 16 + fr;
      const int cl = hb ^ (rB & 7);
      const i32x4 lo = *(const i32x4*)(sB + (rB * 8 + cl) * 16);
      const i32x4 hi = *(const i32x4*)(sB + (rB * 8 + (cl ^ 1)) * 16);
      i32x8 b;
      b[0] = lo[0]; b[1] = lo[1]; b[2] = lo[2]; b[3] = lo[3];
      b[4] = hi[0]; b[5] = hi[1]; b[6] = hi[2]; b[7] = hi[3];
#pragma unroll
      for (int i = 0; i < 4; ++i)
        acc[i][j] = __builtin_amdgcn_mfma_scale_f32_16x16x128_f8f6f4(
            a[i], b, acc[i][j], 0, 0, 0, SCALE1, 0, SCALE1);
    }
    __syncthreads();  // guard LDS overwrite next iter
  }

  // Epilogue. C/D layout (16x16 shapes, dtype/shape-family independent):
  // col = lane&15, row = (lane>>4)*4 + reg.
  const int rq = h * 4;
  float posPart = 0.0f;
  float colAcc[4] = {0.0f, 0.0f, 0.0f, 0.0f};
#pragma unroll
  for (int i = 0; i < 4; ++i) {
    const int rbase = rowBase + wr * 64 + i * 16 + rq;
    float rs[4] = {0.0f, 0.0f, 0.0f, 0.0f};
#pragma unroll
    for (int j = 0; j < 4; ++j) {
      const int colg = colBase + wc * 64 + j * 16 + fr;
      fp32x4 v = acc[i][j];
#pragma unroll
      for (int rg = 0; rg < 4; ++rg) {
        const int rowg = rbase + rg;
        const float sv = v[rg] * INV_T;
        float e = __expf(sv);
        if (diag && rowg == colg) e = 0.0f;  // exclude matrix diagonal exactly
        rs[rg] += e;
        colAcc[j] += e;
        if (colg == rowg + BS) posPart += sv;  // upper copy only; doubled later
      }
    }
#pragma unroll
    for (int rg = 0; rg < 4; ++rg) {
      float s = rs[rg];
      s += __shfl_xor(s, 1);
      s += __shfl_xor(s, 2);
      s += __shfl_xor(s, 4);
      s += __shfl_xor(s, 8);
      if (fr == 0) atomicAdd(&den[rbase + rg], s);
    }
  }
  if (!diag) {
#pragma unroll
    for (int j = 0; j < 4; ++j) {
      float c = colAcc[j];
      c += __shfl_xor(c, 16);
      c += __shfl_xor(c, 32);
      if (h == 0) atomicAdd(&den[colBase + wc * 64 + j * 16 + fr], c);
    }
  }
  posPart += __shfl_xor(posPart, 1);
  posPart += __shfl_xor(posPart, 2);
  posPart += __shfl_xor(posPart, 4);
  posPart += __shfl_xor(posPart, 8);
  posPart += __shfl_xor(posPart, 16);
  posPart += __shfl_xor(posPart, 32);
  if (lane == 0 && posPart != 0.0f) atomicAdd(posAcc, posPart);

  // ---- last-block finalize (no separate dispatch) ----
  __shared__ bool lastFlag;
  __syncthreads();  // all this block's den/posAcc atomics issued
  if (tid == 0) {
    __threadfence();
    unsigned int old = __hip_atomic_fetch_add(counter, 1u, __ATOMIC_ACQ_REL,
                                              __HIP_MEMORY_SCOPE_AGENT);
    lastFlag = (old == NBLK - 1);
  }
  __syncthreads();
  if (lastFlag) {
    float s = 0.0f;
    for (int i = tid; i < NROW; i += 256)
      s += logf(__hip_atomic_load(&den[i], __ATOMIC_RELAXED,
                                  __HIP_MEMORY_SCOPE_AGENT));
#pragma unroll
    for (int off = 1; off < 64; off <<= 1) s += __shfl_xor(s, off);
    __shared__ float wsum[4];
    if ((tid & 63) == 0) wsum[tid >> 6] = s;
    __syncthreads();
    if (tid == 0) {
      const float tot = wsum[0] + wsum[1] + wsum[2] + wsum[3];
      const float pos = __hip_atomic_load(posAcc, __ATOMIC_RELAXED,
                                          __HIP_MEMORY_SCOPE_AGENT);
      out[0] = (tot - 2.0f * pos) * (1.0f / (float)NROW);
    }
  }
}

extern "C" void kernel_launch(void* const* d_in, const int* in_sizes, int n_in,
                              void* d_out, int out_size, void* d_ws, size_t ws_size,
                              hipStream_t stream) {
  const float* zi = (const float*)d_in[0];
  const float* zj = (const float*)d_in[1];
  float* out = (float*)d_out;

  u8* An = (u8*)d_ws;                                     // 4 MB fp8 normalized reps
  float* den = (float*)((char*)d_ws + (size_t)NROW * D);  // 8192 fp32
  float* posAcc = den + NROW;                             // 1 fp32
  unsigned int* counter = (unsigned int*)(posAcc + 1);    // 1 u32

  normalize_k<<<NROW / 4, 256, 0, stream>>>(zi, zj, An, den, posAcc, counter);
  gemm_expsum<<<NBLK, 256, 0, stream>>>(An, den, posAcc, counter, out);
}

// Round 7
// 182.829 us; speedup vs baseline: 1.0795x; 1.0606x over previous
//
#include <hip/hip_runtime.h>

typedef unsigned char u8;
typedef float fp32x4 __attribute__((ext_vector_type(4)));
typedef long i64x2 __attribute__((ext_vector_type(2)));

#define BS 4096
#define NROW 8192
#define D 512
#define TILE 128
#define BK 64                     // k-bytes staged per iter (fp8)
#define NB (NROW / TILE)          // 64 block-rows/cols
#define NBLK (NB * (NB + 1) / 2)  // 2080 upper-triangle blocks
#define INV_T 10.0f

__device__ __forceinline__ void g2l16(const void* g, void* l) {
  __builtin_amdgcn_global_load_lds(
      (const __attribute__((address_space(1))) unsigned int*)g,
      (__attribute__((address_space(3))) unsigned int*)l, 16, 0, 0);
}

// Wave-per-row normalize -> fp8 e4m3 (An is 4 MB: XCD-L2 resident).
// Also zeroes den/posAcc/counter (ws is re-poisoned before every launch).
__global__ __launch_bounds__(256) void normalize_k(
    const float* __restrict__ zi, const float* __restrict__ zj,
    u8* __restrict__ An, float* __restrict__ den, float* __restrict__ posAcc,
    unsigned int* __restrict__ counter) {
  const int lane = threadIdx.x & 63;
  const int wave = threadIdx.x >> 6;
  const int r = blockIdx.x * 4 + wave;
  const float* src = (r < BS) ? (zi + (size_t)r * D) : (zj + (size_t)(r - BS) * D);
  const float4 v0 = ((const float4*)src)[lane * 2];
  const float4 v1 = ((const float4*)src)[lane * 2 + 1];
  float ss = v0.x * v0.x + v0.y * v0.y + v0.z * v0.z + v0.w * v0.w +
             v1.x * v1.x + v1.y * v1.y + v1.z * v1.z + v1.w * v1.w;
#pragma unroll
  for (int off = 1; off < 64; off <<= 1) ss += __shfl_xor(ss, off);
  const float inv = 1.0f / fmaxf(sqrtf(ss), 1e-8f);
  int lo = __builtin_amdgcn_cvt_pk_fp8_f32(v0.x * inv, v0.y * inv, 0, false);
  lo = __builtin_amdgcn_cvt_pk_fp8_f32(v0.z * inv, v0.w * inv, lo, true);
  int hi = __builtin_amdgcn_cvt_pk_fp8_f32(v1.x * inv, v1.y * inv, 0, false);
  hi = __builtin_amdgcn_cvt_pk_fp8_f32(v1.z * inv, v1.w * inv, hi, true);
  ((int2*)(An + (size_t)r * D))[lane] = make_int2(lo, hi);
  if (lane == 0) den[r] = 0.0f;
  if (r == 0 && lane == 0) {
    posAcc[0] = 0.0f;
    counter[0] = 0u;
  }
}

// Upper-triangle (bi<=bj) 128x128 tiles of sim = An*An^T. fp8 K=32 MFMA,
// BK=64, single-buffered 16 KB LDS, 2-barrier K-loop (R4 structure — dbuf
// regressed twice, occupancy is the latency-hider).
// Fragment reads are ds_read_b128 under a K-permutation: a lane's 16 staged
// bytes = low 8 -> sub-MFMA 0, high 8 -> sub-MFMA 1. A and B share the
// permutation, so the K=64 dot product is exact. With the 16B-granular
// (row>>1)&3 chunk-xor, every 8-lane phase covers all 32 banks (R2's
// measured-zero pattern) -> conflict-free, and half the LDS instructions
// of R4's b64 reads.
// Off-diagonal tiles: den[row] += rowsum(exp), den[col] += colsum(exp).
// Diagonal tiles: den[row] += rowsum(exp), row==col masked.
// posAcc += sim/T over entries col == row+BS (upper copy; doubled at end).
// Last block to finish (agent-scope counter) computes the final loss.
__global__ __launch_bounds__(256) void gemm_expsum(
    const u8* __restrict__ An, float* __restrict__ den,
    float* __restrict__ posAcc, unsigned int* __restrict__ counter,
    float* __restrict__ out) {
  __shared__ __align__(16) u8 sA[TILE * BK];  // 8 KB
  __shared__ __align__(16) u8 sB[TILE * BK];  // 8 KB

  // linear triangle order: consecutive blocks share the A-strip (L2 reuse)
  int rem = blockIdx.x;
  int bi = 0;
  while (rem >= NB - bi) { rem -= NB - bi; ++bi; }
  const int bj = bi + rem;
  const bool diag = (bi == bj);
  const int rowBase = bi * TILE;
  const int colBase = bj * TILE;

  const int tid = threadIdx.x;
  const int lane = tid & 63;
  const int wave = tid >> 6;
  const int wr = wave >> 1;
  const int wc = wave & 1;

  fp32x4 acc[4][4] = {};

  // staging: 512 16B chunks per tile (row = c>>2, 4 chunks per 64B row);
  // LDS slot (row, q) holds global chunk q ^ ((row>>1)&3)  [R4's mapping].
  const int c0 = tid;
  const int c1 = tid + 256;
  const int r0 = c0 >> 2, q0 = (c0 & 3) ^ ((r0 >> 1) & 3);
  const int r1 = c1 >> 2, q1 = (c1 & 3) ^ ((r1 >> 1) & 3);
  const u8* gA0 = An + (size_t)(rowBase + r0) * D + q0 * 16;
  const u8* gA1 = An + (size_t)(rowBase + r1) * D + q1 * 16;
  const u8* gB0 = An + (size_t)(colBase + r0) * D + q0 * 16;
  const u8* gB1 = An + (size_t)(colBase + r1) * D + q1 * 16;
  u8* lA0 = sA + c0 * 16;
  u8* lA1 = sA + c1 * 16;
  u8* lB0 = sB + c0 * 16;
  u8* lB1 = sB + c1 * 16;

  const int fr = lane & 15;  // A row / B col within 16-tile
  const int h = lane >> 4;   // k-group 0..3: global chunk h = this lane's 16B

  for (int k0 = 0; k0 < D; k0 += BK) {
    g2l16(gA0 + k0, lA0);
    g2l16(gA1 + k0, lA1);
    g2l16(gB0 + k0, lB0);
    g2l16(gB1 + k0, lB1);
    __syncthreads();  // drains vmcnt -> LDS tiles complete

    i64x2 a[4], b[4];
#pragma unroll
    for (int i = 0; i < 4; ++i) {
      const int rA = wr * 64 + i * 16 + fr;
      const int rB = wc * 64 + i * 16 + fr;
      a[i] = *(const i64x2*)(sA + (rA * 4 + (h ^ ((rA >> 1) & 3))) * 16);
      b[i] = *(const i64x2*)(sB + (rB * 4 + (h ^ ((rB >> 1) & 3))) * 16);
    }
#pragma unroll
    for (int i = 0; i < 4; ++i)
#pragma unroll
      for (int j = 0; j < 4; ++j) {
        acc[i][j] = __builtin_amdgcn_mfma_f32_16x16x32_fp8_fp8(
            a[i][0], b[j][0], acc[i][j], 0, 0, 0);
        acc[i][j] = __builtin_amdgcn_mfma_f32_16x16x32_fp8_fp8(
            a[i][1], b[j][1], acc[i][j], 0, 0, 0);
      }
    __syncthreads();  // guard LDS overwrite next iter
  }

  // Epilogue. C/D layout (16x16 shapes, dtype-independent):
  // col = lane&15, row = (lane>>4)*4 + reg.
  const int rq = h * 4;
  float posPart = 0.0f;
  float colAcc[4] = {0.0f, 0.0f, 0.0f, 0.0f};
#pragma unroll
  for (int i = 0; i < 4; ++i) {
    const int rbase = rowBase + wr * 64 + i * 16 + rq;
    float rs[4] = {0.0f, 0.0f, 0.0f, 0.0f};
#pragma unroll
    for (int j = 0; j < 4; ++j) {
      const int colg = colBase + wc * 64 + j * 16 + fr;
      fp32x4 v = acc[i][j];
#pragma unroll
      for (int rg = 0; rg < 4; ++rg) {
        const int rowg = rbase + rg;
        const float sv = v[rg] * INV_T;
        float e = __expf(sv);
        if (diag && rowg == colg) e = 0.0f;  // exclude matrix diagonal exactly
        rs[rg] += e;
        colAcc[j] += e;
        if (colg == rowg + BS) posPart += sv;  // upper copy only; doubled later
      }
    }
#pragma unroll
    for (int rg = 0; rg < 4; ++rg) {
      float s = rs[rg];
      s += __shfl_xor(s, 1);
      s += __shfl_xor(s, 2);
      s += __shfl_xor(s, 4);
      s += __shfl_xor(s, 8);
      if (fr == 0) atomicAdd(&den[rbase + rg], s);
    }
  }
  if (!diag) {
#pragma unroll
    for (int j = 0; j < 4; ++j) {
      float c = colAcc[j];
      c += __shfl_xor(c, 16);
      c += __shfl_xor(c, 32);
      if (h == 0) atomicAdd(&den[colBase + wc * 64 + j * 16 + fr], c);
    }
  }
  posPart += __shfl_xor(posPart, 1);
  posPart += __shfl_xor(posPart, 2);
  posPart += __shfl_xor(posPart, 4);
  posPart += __shfl_xor(posPart, 8);
  posPart += __shfl_xor(posPart, 16);
  posPart += __shfl_xor(posPart, 32);
  if (lane == 0 && posPart != 0.0f) atomicAdd(posAcc, posPart);

  // ---- last-block finalize (no separate dispatch) ----
  __shared__ bool lastFlag;
  __syncthreads();  // all this block's den/posAcc atomics issued
  if (tid == 0) {
    __threadfence();
    unsigned int old = __hip_atomic_fetch_add(counter, 1u, __ATOMIC_ACQ_REL,
                                              __HIP_MEMORY_SCOPE_AGENT);
    lastFlag = (old == NBLK - 1);
  }
  __syncthreads();
  if (lastFlag) {
    float s = 0.0f;
    for (int i = tid; i < NROW; i += 256)
      s += logf(__hip_atomic_load(&den[i], __ATOMIC_RELAXED,
                                  __HIP_MEMORY_SCOPE_AGENT));
#pragma unroll
    for (int off = 1; off < 64; off <<= 1) s += __shfl_xor(s, off);
    __shared__ float wsum[4];
    if ((tid & 63) == 0) wsum[tid >> 6] = s;
    __syncthreads();
    if (tid == 0) {
      const float tot = wsum[0] + wsum[1] + wsum[2] + wsum[3];
      const float pos = __hip_atomic_load(posAcc, __ATOMIC_RELAXED,
                                          __HIP_MEMORY_SCOPE_AGENT);
      out[0] = (tot - 2.0f * pos) * (1.0f / (float)NROW);
    }
  }
}

extern "C" void kernel_launch(void* const* d_in, const int* in_sizes, int n_in,
                              void* d_out, int out_size, void* d_ws, size_t ws_size,
                              hipStream_t stream) {
  const float* zi = (const float*)d_in[0];
  const float* zj = (const float*)d_in[1];
  float* out = (float*)d_out;

  u8* An = (u8*)d_ws;                                     // 4 MB fp8 normalized reps
  float* den = (float*)((char*)d_ws + (size_t)NROW * D);  // 8192 fp32
  float* posAcc = den + NROW;                             // 1 fp32
  unsigned int* counter = (unsigned int*)(posAcc + 1);    // 1 u32

  normalize_k<<<NROW / 4, 256, 0, stream>>>(zi, zj, An, den, posAcc, counter);
  gemm_expsum<<<NBLK, 256, 0, stream>>>(An, den, posAcc, counter, out);
}